// Round 10
// baseline (248.161 us; speedup 1.0000x reference)
//
#include <hip/hip_runtime.h>
#include <hip/hip_bf16.h>
#include <stdint.h>

#define BZv 4
#define QL 512
#define CL 1536
#define KVL 2048
#define EMB 1024
#define NH 16
#define HD 64
#define QSCALE 0.18033688011112042f  /* 0.125 * log2(e) */
#define NG 2048                       /* partial groups: 64 hb * 8 qt * 4 waves */
#define NSEG 3

typedef __attribute__((ext_vector_type(8))) short short8;
typedef __attribute__((ext_vector_type(4))) float floatx4;
typedef __attribute__((ext_vector_type(4))) float fx4;

__device__ __forceinline__ unsigned short f2b(float f) {
  union { float f; unsigned int u; } v; v.f = f;
  return (unsigned short)((v.u + 0x7FFFu + ((v.u >> 16) & 1u)) >> 16);
}

__device__ __forceinline__ unsigned pku(float a, float b) {
  union { __hip_bfloat162 h; unsigned u; } c;
  c.h = __float22bfloat162_rn(make_float2(a, b));
  return c.u;   // low 16 = a, high 16 = b
}

__device__ __forceinline__ short8 cvt8(fx4 a, fx4 b) {
  short8 r;
  r[0] = (short)f2b(a.x); r[1] = (short)f2b(a.y);
  r[2] = (short)f2b(a.z); r[3] = (short)f2b(a.w);
  r[4] = (short)f2b(b.x); r[5] = (short)f2b(b.y);
  r[6] = (short)f2b(b.z); r[7] = (short)f2b(b.w);
  return r;
}
__device__ __forceinline__ short8 cvt8w(fx4 a, fx4 b, float w) {
  short8 r;
  r[0] = (short)f2b(a.x * w); r[1] = (short)f2b(a.y * w);
  r[2] = (short)f2b(a.z * w); r[3] = (short)f2b(a.w * w);
  r[4] = (short)f2b(b.x * w); r[5] = (short)f2b(b.y * w);
  r[6] = (short)f2b(b.z * w); r[7] = (short)f2b(b.w * w);
  return r;
}

#if __has_builtin(__builtin_amdgcn_exp2f)
#define EXP2F(x) __builtin_amdgcn_exp2f(x)
#else
#define EXP2F(x) exp2f(x)
#endif

__device__ __forceinline__ void gload_lds16(const void* g, void* l) {
  __builtin_amdgcn_global_load_lds(
      (const __attribute__((address_space(1))) unsigned char*)g,
      (__attribute__((address_space(3))) unsigned char*)l, 16, 0, 0);
}

#define BAR_LIGHT() asm volatile("s_barrier" ::: "memory")
#define BAR_K() asm volatile("s_waitcnt vmcnt(3) lgkmcnt(0)\n\ts_barrier" ::: "memory")

// ---------------- prep v4: hoisted loads (12 loads in flight/thread) ----------
__global__ __launch_bounds__(256) void prep_kernel(
    const float* __restrict__ hid, const float* __restrict__ Wq, const float* __restrict__ Wk,
    const float* __restrict__ Wv, const float* __restrict__ Wo,
    const float* __restrict__ kc, const float* __restrict__ vc, const float* __restrict__ msk,
    unsigned short* __restrict__ Xb, unsigned short* __restrict__ Wqb, unsigned short* __restrict__ Wkb,
    unsigned short* __restrict__ Wvb, unsigned short* __restrict__ Wob,
    unsigned short* __restrict__ Kb, unsigned short* __restrict__ Vb,
    float* __restrict__ kf, float* __restrict__ vf, unsigned short* __restrict__ wb)
{
  const int blk = blockIdx.x, tid = threadIdx.x;
  if (blk < 768) {
    const float* src; unsigned short* dst; int base;
    if (blk < 256) { src = hid; dst = Xb; base = blk * 2048; }
    else {
      int w = (blk - 256) >> 7, wo = (blk - 256) & 127;
      src = (w == 0) ? Wq : (w == 1) ? Wk : (w == 2) ? Wv : Wo;
      dst = (w == 0) ? Wqb : (w == 1) ? Wkb : (w == 2) ? Wvb : Wob;
      base = wo * 2048;
    }
    const fx4* s4 = (const fx4*)src;
    short8* d8 = (short8*)dst;
    fx4 v[8];
#pragma unroll
    for (int it = 0; it < 4; ++it) {
      int u = base + it * 512 + tid * 2;
      v[2 * it] = s4[u]; v[2 * it + 1] = s4[u + 1];
    }
#pragma unroll
    for (int it = 0; it < 4; ++it) {
      int u = base + it * 512 + tid * 2;
      d8[u >> 1] = cvt8(v[2 * it], v[2 * it + 1]);
    }
  } else if (blk < 1792) {
    const bool isV = blk >= 1280;
    const int r = blk - (isV ? 1280 : 768);
    const int bb = r >> 7, ko = r & 127;
    const fx4* s4 = (const fx4*)((isV ? vc : kc) + (long)bb * CL * EMB);
    fx4* f4 = (fx4*)((isV ? vf : kf) + (long)bb * KVL * EMB);
    short8* b8 = (short8*)((isV ? Vb : Kb) + (long)bb * KVL * EMB);
    const float* mrow = msk + bb * KVL;
    fx4 v[12];
#pragma unroll
    for (int it = 0; it < 6; ++it) {
      int u = ko * 3072 + it * 512 + tid * 2;
      v[2 * it] = s4[u]; v[2 * it + 1] = s4[u + 1];
    }
#pragma unroll
    for (int it = 0; it < 6; ++it) {
      int u = ko * 3072 + it * 512 + tid * 2;
      f4[u] = v[2 * it]; f4[u + 1] = v[2 * it + 1];
      if (isV) {
        float w = __expf(mrow[u >> 8]);   // u even: both halves share the row
        b8[u >> 1] = cvt8w(v[2 * it], v[2 * it + 1], w);
      } else {
        b8[u >> 1] = cvt8(v[2 * it], v[2 * it + 1]);
      }
    }
  } else {
    const fx4* m4 = (const fx4*)msk;
    short8* w8 = (short8*)wb;
#pragma unroll
    for (int it = 0; it < 4; ++it) {
      int u = it * 512 + tid * 2;
      fx4 a = m4[u], b = m4[u + 1];
      fx4 ea, eb;
      ea.x = __expf(a.x); ea.y = __expf(a.y); ea.z = __expf(a.z); ea.w = __expf(a.w);
      eb.x = __expf(b.x); eb.y = __expf(b.y); eb.z = __expf(b.z); eb.w = __expf(b.w);
      w8[u >> 1] = cvt8(ea, eb);
    }
  }
}

// ---------------- fused QKV GEMM v2: 128x64 tiles, BK=64, grid (48,16) --------
__global__ __launch_bounds__(256) void qkv_gemm(
    const unsigned short* __restrict__ Xb,
    const unsigned short* __restrict__ Wqb, const unsigned short* __restrict__ Wkb,
    const unsigned short* __restrict__ Wvb,
    const float* __restrict__ bq, const float* __restrict__ bk, const float* __restrict__ bv,
    const float* __restrict__ msk,
    unsigned short* __restrict__ Qb, unsigned short* __restrict__ Kb, unsigned short* __restrict__ Vb,
    float* __restrict__ kf, float* __restrict__ vf)
{
  __shared__ unsigned short At[128 * 64];   // row: 128B = 8 chunks of 16B, chunk-XOR swizzled
  __shared__ unsigned short Bt[64 * 64];
  const int tid = threadIdx.x, lane = tid & 63, wave = tid >> 6;
  const int quad = lane >> 4, l = lane & 15;
  const int sw = l & 7;
  const int mat = blockIdx.x >> 4;
  const int ncol = (blockIdx.x & 15) * 64;
  const int mbase = blockIdx.y * 128;
  const unsigned short* W = (mat == 0) ? Wqb : (mat == 1) ? Wkb : Wvb;
  const float* bias = (mat == 0) ? bq : (mat == 1) ? bk : bv;
  const int rh = wave * 32;

  floatx4 zero = {0.f, 0.f, 0.f, 0.f};
  floatx4 acc[2][4];
#pragma unroll
  for (int i = 0; i < 2; i++)
#pragma unroll
    for (int j = 0; j < 4; j++) acc[i][j] = zero;

  for (int k0 = 0; k0 < EMB; k0 += 64) {
    if (k0) BAR_LIGHT();
#pragma unroll
    for (int s = 0; s < 4; s++) {
      int g = s * 256 + tid;
      int r = g >> 3, c = g & 7;
      gload_lds16(Xb + (size_t)(mbase + r) * EMB + k0 + ((c ^ (r & 7)) * 8), &At[g * 8]);
    }
#pragma unroll
    for (int s = 0; s < 2; s++) {
      int g = s * 256 + tid;
      int r = g >> 3, c = g & 7;
      gload_lds16(W + (size_t)(ncol + r) * EMB + k0 + ((c ^ (r & 7)) * 8), &Bt[g * 8]);
    }
    __syncthreads();
    short8 af[2][2], bfr[4][2];
#pragma unroll
    for (int rt = 0; rt < 2; rt++) {
      const unsigned short* p = &At[(rh + rt * 16 + l) * 64];
      af[rt][0] = *(const short8*)&p[(quad ^ sw) * 8];
      af[rt][1] = *(const short8*)&p[((quad + 4) ^ sw) * 8];
    }
#pragma unroll
    for (int ct = 0; ct < 4; ct++) {
      const unsigned short* p = &Bt[(ct * 16 + l) * 64];
      bfr[ct][0] = *(const short8*)&p[(quad ^ sw) * 8];
      bfr[ct][1] = *(const short8*)&p[((quad + 4) ^ sw) * 8];
    }
#pragma unroll
    for (int rt = 0; rt < 2; rt++)
#pragma unroll
      for (int ct = 0; ct < 4; ct++) {
        acc[rt][ct] = __builtin_amdgcn_mfma_f32_16x16x32_bf16(af[rt][0], bfr[ct][0], acc[rt][ct], 0, 0, 0);
        acc[rt][ct] = __builtin_amdgcn_mfma_f32_16x16x32_bf16(af[rt][1], bfr[ct][1], acc[rt][ct], 0, 0, 0);
      }
  }

#pragma unroll
  for (int ct = 0; ct < 4; ct++) {
    int col = ncol + ct * 16 + l;
    float bb = bias[col];
#pragma unroll
    for (int rt = 0; rt < 2; rt++)
#pragma unroll
      for (int r = 0; r < 4; r++) {
        int m = mbase + rh + rt * 16 + quad * 4 + r;
        float val = acc[rt][ct][r] + bb;
        if (mat == 0) {
          Qb[(size_t)m * EMB + col] = f2b(val * QSCALE);
        } else {
          size_t a = ((size_t)(m >> 9) * KVL + CL + (m & 511)) * EMB + col;
          if (mat == 1) { Kb[a] = f2b(val); kf[a] = val; }
          else {
            float w = __expf(msk[(m >> 9) * KVL + CL + (m & 511)]);
            Vb[a] = f2b(val * w); vf[a] = val;
          }
        }
      }
  }
}

// ---------------- O-proj GEMM v2: 64x64 tiles, BK=64, grid (16,32) ------------
__global__ __launch_bounds__(256) void oproj_gemm(
    const unsigned short* __restrict__ A, const unsigned short* __restrict__ W,
    const float* __restrict__ bias, float* __restrict__ out)
{
  __shared__ unsigned short At[64 * 64];
  __shared__ unsigned short Bt[64 * 64];
  const int tid = threadIdx.x, lane = tid & 63, wave = tid >> 6;
  const int quad = lane >> 4, l = lane & 15;
  const int sw = l & 7;
  const int ncol = blockIdx.x * 64;
  const int mbase = blockIdx.y * 64;
  const int rh = (wave & 1) * 32, ch = (wave >> 1) * 32;

  floatx4 zero = {0.f, 0.f, 0.f, 0.f};
  floatx4 acc[2][2];
#pragma unroll
  for (int i = 0; i < 2; i++)
#pragma unroll
    for (int j = 0; j < 2; j++) acc[i][j] = zero;

  for (int k0 = 0; k0 < EMB; k0 += 64) {
    if (k0) BAR_LIGHT();
#pragma unroll
    for (int s = 0; s < 2; s++) {
      int g = s * 256 + tid;
      int r = g >> 3, c = g & 7;
      gload_lds16(A + (size_t)(mbase + r) * EMB + k0 + ((c ^ (r & 7)) * 8), &At[g * 8]);
      gload_lds16(W + (size_t)(ncol + r) * EMB + k0 + ((c ^ (r & 7)) * 8), &Bt[g * 8]);
    }
    __syncthreads();
    short8 af[2][2], bfr[2][2];
#pragma unroll
    for (int rt = 0; rt < 2; rt++) {
      const unsigned short* p = &At[(rh + rt * 16 + l) * 64];
      af[rt][0] = *(const short8*)&p[(quad ^ sw) * 8];
      af[rt][1] = *(const short8*)&p[((quad + 4) ^ sw) * 8];
    }
#pragma unroll
    for (int ct = 0; ct < 2; ct++) {
      const unsigned short* p = &Bt[(ch + ct * 16 + l) * 64];
      bfr[ct][0] = *(const short8*)&p[(quad ^ sw) * 8];
      bfr[ct][1] = *(const short8*)&p[((quad + 4) ^ sw) * 8];
    }
#pragma unroll
    for (int rt = 0; rt < 2; rt++)
#pragma unroll
      for (int ct = 0; ct < 2; ct++) {
        acc[rt][ct] = __builtin_amdgcn_mfma_f32_16x16x32_bf16(af[rt][0], bfr[ct][0], acc[rt][ct], 0, 0, 0);
        acc[rt][ct] = __builtin_amdgcn_mfma_f32_16x16x32_bf16(af[rt][1], bfr[ct][1], acc[rt][ct], 0, 0, 0);
      }
  }

#pragma unroll
  for (int ct = 0; ct < 2; ct++) {
    int col = ncol + ch + ct * 16 + l;
    float bb = bias[col];
#pragma unroll
    for (int rt = 0; rt < 2; rt++)
#pragma unroll
      for (int r = 0; r < 4; r++) {
        int m = mbase + rh + rt * 16 + quad * 4 + r;
        out[(size_t)m * EMB + col] = acc[rt][ct][r] + bb;
      }
  }
}

// ---------------- flash attention v9: split-KV x3, in-register P exchange -----
// Pl LDS buffer removed: QK^T output (lane holds P[kv=16c+4*quad+r][q=l]) is
// redistributed to the PV B-frag layout (P[kv=8*quad+j][q=l]) via 16 __shfl:
// word w of pf0 = packed u[c=quad>>1][w&1] from lane 32*(quad&1)+l+16*(w>>1);
// pf1 same with c+2. LDS 25.7 KB -> 6 blocks/CU; grid 1536 = exactly 6/CU.
__global__ __launch_bounds__(256, 4) void attn_kernel(
    const unsigned short* __restrict__ Qb, const unsigned short* __restrict__ Kb,
    const unsigned short* __restrict__ Vb, const unsigned short* __restrict__ wb,
    float* __restrict__ PO, float* __restrict__ PM, float* __restrict__ PD)
{
  __shared__ unsigned short Kt[2][64 * 64];   // linear rows (128B), swizzled chunks
  __shared__ unsigned short Vt[65 * 72];      // rows 0..63 = V^T[d][kv], row 64 = w[kv]

  const int bid = blockIdx.x;
  const int seg = bid >> 9;                    // 0..2
  const int id = bid & 511;
  const int hb = id & 63, qt = id >> 6;
  const int b = hb >> 4, h = hb & 15;
  const int tid = threadIdx.x, lane = tid & 63, wave = tid >> 6;
  const int quad = lane >> 4, l = lane & 15;
  const int qbase = qt * 64 + wave * 16;

  const int nt_tot = (CL >> 6) + qt + 1;      // 25..32 tiles of 64 kv
  const int n1 = nt_tot / 3, n2 = (2 * nt_tot) / 3;
  const int t_beg = (seg == 0) ? 0 : (seg == 1) ? n1 : n2;
  const int t_end = (seg == 0) ? n1 : (seg == 1) ? n2 : nt_tot;

  const unsigned short* qp = Qb + (size_t)(b * QL + qbase + l) * EMB + h * HD + quad * 8;
  const short8 bq0 = *(const short8*)qp;
  const short8 bq1 = *(const short8*)(qp + 32);

  floatx4 zero = {0.f, 0.f, 0.f, 0.f};
  floatx4 o[4], o4 = zero;
#pragma unroll
  for (int c = 0; c < 4; c++) o[c] = zero;
  float mr = -INFINITY;                        // per-lane state for q = l

  const int vp = tid & 31, vg = tid >> 5;
  const unsigned short* vsrc = Vb + (size_t)(b * KVL) * EMB + h * HD + vg * 8;
  const unsigned short* wsrc = wb + (size_t)b * KVL + 2 * vp;
  const unsigned short* ksrc = Kb + (size_t)(b * KVL) * EMB + h * HD;
  const int sw = l & 7;                        // read-side chunk XOR

  uint4 va, vbr; ushort2 wn;
  auto VLOAD = [&](int t) {
    const unsigned short* vs = vsrc + (size_t)(t * 64 + 2 * vp) * EMB;
    va = *(const uint4*)vs;
    vbr = *(const uint4*)(vs + EMB);
    wn = *(const ushort2*)(wsrc + t * 64);   // uniform: every wave issues 3 V loads
  };
  auto VSTAGE = [&]() {
    const unsigned short* pa = (const unsigned short*)&va;
    const unsigned short* pb = (const unsigned short*)&vbr;
#pragma unroll
    for (int j = 0; j < 8; j++) {
      ushort2 tt; tt.x = pa[j]; tt.y = pb[j];
      *(ushort2*)&Vt[(vg * 8 + j) * 72 + 2 * vp] = tt;
    }
    if (vg == 0) *(ushort2*)&Vt[64 * 72 + 2 * vp] = wn;
  };
  auto GLOAD_K = [&](int t, int buf) {
    const int kv0 = t * 64;
#pragma unroll
    for (int s = 0; s < 2; s++) {
      int g = s * 256 + tid;
      int r = g >> 3, k = g & 7;
      gload_lds16(ksrc + (size_t)(kv0 + r) * EMB + ((k ^ (r & 7)) * 8),
                  &Kt[buf][g * 8]);
    }
  };

  // prologue (full drains; one-time cost)
  VLOAD(t_beg);
  GLOAD_K(t_beg, 0);
  __syncthreads();
  VSTAGE();
  if (t_beg + 1 < t_end) VLOAD(t_beg + 1);
  __syncthreads();

  const int la = 32 * (quad & 1) + l;          // P-exchange source lane
  const bool chi = (quad & 2) != 0;

  int cur = 0;
  for (int t = t_beg; t < t_end; ++t) {
    if (t + 1 < t_end) GLOAD_K(t + 1, cur ^ 1);   // oldest vmem: 2 gload_lds
    const int kv0 = t * 64;
    floatx4 s[4];
#pragma unroll
    for (int c = 0; c < 4; c++) {
      const int rr = c * 16 + l;
      const unsigned short* krow = &Kt[cur][rr * 64];
      short8 k0 = *(const short8*)&krow[(quad ^ sw) * 8];
      short8 k1 = *(const short8*)&krow[((quad + 4) ^ sw) * 8];
      s[c] = __builtin_amdgcn_mfma_f32_16x16x32_bf16(k0, bq0, zero, 0, 0, 0);
      s[c] = __builtin_amdgcn_mfma_f32_16x16x32_bf16(k1, bq1, s[c], 0, 0, 0);
    }
    if (kv0 + 63 > CL + qbase) {
      const int lim = CL + qbase + l;
#pragma unroll
      for (int c = 0; c < 4; c++) {
        int kvb = kv0 + c * 16 + quad * 4;
#pragma unroll
        for (int r = 0; r < 4; r++)
          s[c][r] = (kvb + r <= lim) ? s[c][r] : -INFINITY;
      }
    }
    float u0 = fmaxf(fmaxf(s[0][0], s[0][1]), fmaxf(s[0][2], s[0][3]));
    float u1 = fmaxf(fmaxf(s[1][0], s[1][1]), fmaxf(s[1][2], s[1][3]));
    float u2 = fmaxf(fmaxf(s[2][0], s[2][1]), fmaxf(s[2][2], s[2][3]));
    float u3 = fmaxf(fmaxf(s[3][0], s[3][1]), fmaxf(s[3][2], s[3][3]));
    float lmax = fmaxf(fmaxf(u0, u1), fmaxf(u2, u3));
    lmax = fmaxf(lmax, __shfl_xor(lmax, 16, 64));
    lmax = fmaxf(lmax, __shfl_xor(lmax, 32, 64));
    float mnew = fmaxf(mr, lmax);
    float alpha = EXP2F(mr - mnew);
    mr = mnew;
    // P~ = exp2(s - mnew) packed to bf16 pairs (plo = kv pair r0,r1; phi = r2,r3)
    unsigned plo[4], phi[4];
#pragma unroll
    for (int c = 0; c < 4; c++) {
      float p0 = EXP2F(s[c][0] - mnew), p1 = EXP2F(s[c][1] - mnew);
      float p2 = EXP2F(s[c][2] - mnew), p3 = EXP2F(s[c][3] - mnew);
      plo[c] = pku(p0, p1); phi[c] = pku(p2, p3);
    }
#pragma unroll
    for (int c = 0; c < 4; c++)
#pragma unroll
      for (int r = 0; r < 4; r++) o[c][r] *= alpha;
#pragma unroll
    for (int r = 0; r < 4; r++) o4[r] *= alpha;
    // in-register exchange: 16 shfl + 8 selects (replaces Pl LDS round-trip)
    unsigned a0 = (unsigned)__shfl((int)plo[0], la), a1 = (unsigned)__shfl((int)plo[1], la);
    unsigned b0 = (unsigned)__shfl((int)phi[0], la), b1 = (unsigned)__shfl((int)phi[1], la);
    unsigned c0 = (unsigned)__shfl((int)plo[0], la + 16), c1 = (unsigned)__shfl((int)plo[1], la + 16);
    unsigned d0 = (unsigned)__shfl((int)phi[0], la + 16), d1 = (unsigned)__shfl((int)phi[1], la + 16);
    unsigned e0 = (unsigned)__shfl((int)plo[2], la), e1 = (unsigned)__shfl((int)plo[3], la);
    unsigned f0 = (unsigned)__shfl((int)phi[2], la), f1 = (unsigned)__shfl((int)phi[3], la);
    unsigned g0 = (unsigned)__shfl((int)plo[2], la + 16), g1 = (unsigned)__shfl((int)plo[3], la + 16);
    unsigned h0 = (unsigned)__shfl((int)phi[2], la + 16), h1 = (unsigned)__shfl((int)phi[3], la + 16);
    union { unsigned u[4]; short8 s8; } P0, P1;
    P0.u[0] = chi ? a1 : a0;  P0.u[1] = chi ? b1 : b0;
    P0.u[2] = chi ? c1 : c0;  P0.u[3] = chi ? d1 : d0;
    P1.u[0] = chi ? e1 : e0;  P1.u[1] = chi ? f1 : f0;
    P1.u[2] = chi ? g1 : g0;  P1.u[3] = chi ? h1 : h0;
    short8 pf0 = P0.s8, pf1 = P1.s8;
    short8 vw0 = *(const short8*)&Vt[64 * 72 + quad * 8];
    short8 vw1 = *(const short8*)&Vt[64 * 72 + 32 + quad * 8];
    o4 = __builtin_amdgcn_mfma_f32_16x16x32_bf16(vw0, pf0, o4, 0, 0, 0);
    o4 = __builtin_amdgcn_mfma_f32_16x16x32_bf16(vw1, pf1, o4, 0, 0, 0);
#pragma unroll
    for (int c = 0; c < 4; c++) {
      short8 a0v = *(const short8*)&Vt[(c * 16 + l) * 72 + quad * 8];
      short8 a1v = *(const short8*)&Vt[(c * 16 + l) * 72 + 32 + quad * 8];
      o[c] = __builtin_amdgcn_mfma_f32_16x16x32_bf16(a0v, pf0, o[c], 0, 0, 0);
      o[c] = __builtin_amdgcn_mfma_f32_16x16x32_bf16(a1v, pf1, o[c], 0, 0, 0);
    }
    BAR_LIGHT();                   // barrier1: Vt reads done (exec order); no drain
    if (t + 1 < t_end) {
      VSTAGE();
      if (t + 2 < t_end) VLOAD(t + 2);
    }
    BAR_K();                       // barrier2: drain K gloads + ds_writes only
    cur ^= 1;
  }

  // epilogue: store partials (nontemporal; single-use stream)
  const int gid = hb * 32 + qt * 4 + wave;
  float* po = PO + ((size_t)(seg * NG + gid)) * 1024 + l * 64;
#pragma unroll
  for (int c = 0; c < 4; c++)
    __builtin_nontemporal_store(o[c], (floatx4*)&po[c * 16 + quad * 4]);
  if (quad == 0) {
    __builtin_nontemporal_store(mr, &PM[(size_t)(seg * NG + gid) * 16 + l]);
    __builtin_nontemporal_store(o4[0], &PD[(size_t)(seg * NG + gid) * 16 + l]);
  }
}

// ---------------- combine the 3 KV-split partials -> Cb (bf16) ----------------
__global__ __launch_bounds__(256) void attn_combine(
    const float* __restrict__ PO, const float* __restrict__ PM, const float* __restrict__ PD,
    unsigned short* __restrict__ Cb)
{
  const int tid = threadIdx.x, wave = tid >> 6, lane = tid & 63;
  const int quad = lane >> 4, l = lane & 15;
  const int gid = blockIdx.x * 4 + wave;       // 0..2047
  const int hb = gid >> 5, qt = (gid >> 2) & 7, wv = gid & 3;
  const int b = hb >> 4, h = hb & 15;
  const int q = qt * 64 + wv * 16 + l;

  float m0 = __builtin_nontemporal_load(&PM[(size_t)gid * 16 + l]);
  float m1 = __builtin_nontemporal_load(&PM[(size_t)(NG + gid) * 16 + l]);
  float m2 = __builtin_nontemporal_load(&PM[(size_t)(2 * NG + gid) * 16 + l]);
  float d0 = __builtin_nontemporal_load(&PD[(size_t)gid * 16 + l]);
  float d1 = __builtin_nontemporal_load(&PD[(size_t)(NG + gid) * 16 + l]);
  float d2 = __builtin_nontemporal_load(&PD[(size_t)(2 * NG + gid) * 16 + l]);
  float M = fmaxf(m0, fmaxf(m1, m2));
  float a0 = EXP2F(m0 - M), a1 = EXP2F(m1 - M), a2 = EXP2F(m2 - M);
  float inv = 1.0f / (d0 * a0 + d1 * a1 + d2 * a2);
  a0 *= inv; a1 *= inv; a2 *= inv;

  const fx4* p0 = (const fx4*)(PO + (size_t)gid * 1024 + l * 64 + quad * 16);
  const fx4* p1 = (const fx4*)((const float*)p0 + (size_t)NG * 1024);
  const fx4* p2 = (const fx4*)((const float*)p0 + (size_t)2 * NG * 1024);
  unsigned short* cp = Cb + (size_t)(b * QL + q) * EMB + h * HD + quad * 16;
#pragma unroll
  for (int v = 0; v < 4; v++) {
    fx4 x0 = __builtin_nontemporal_load(p0 + v);
    fx4 x1 = __builtin_nontemporal_load(p1 + v);
    fx4 x2 = __builtin_nontemporal_load(p2 + v);
    ushort4 w4;
    w4.x = f2b(x0.x * a0 + x1.x * a1 + x2.x * a2);
    w4.y = f2b(x0.y * a0 + x1.y * a1 + x2.y * a2);
    w4.z = f2b(x0.z * a0 + x1.z * a1 + x2.z * a2);
    w4.w = f2b(x0.w * a0 + x1.w * a1 + x2.w * a2);
    *(ushort4*)(cp + v * 4) = w4;
  }
}

extern "C" void kernel_launch(void* const* d_in, const int* in_sizes, int n_in,
                              void* d_out, int out_size, void* d_ws, size_t ws_size,
                              hipStream_t stream) {
  const float* hid  = (const float*)d_in[0];
  const float* mask = (const float*)d_in[1];
  const float* kc   = (const float*)d_in[2];
  const float* vc   = (const float*)d_in[3];
  const float* Wq   = (const float*)d_in[4];
  const float* bq   = (const float*)d_in[5];
  const float* Wk   = (const float*)d_in[6];
  const float* bk   = (const float*)d_in[7];
  const float* Wv   = (const float*)d_in[8];
  const float* bv   = (const float*)d_in[9];
  const float* Wo   = (const float*)d_in[10];
  const float* bo   = (const float*)d_in[11];

  float* out_f = (float*)d_out;
  float* kf = out_f + (size_t)BZv * QL * EMB;
  float* vf = kf + (size_t)BZv * KVL * EMB;

  char* p = (char*)d_ws;
  unsigned short* Xb  = (unsigned short*)p; p += (size_t)BZv * QL * EMB * 2;
  unsigned short* Wqb = (unsigned short*)p; p += (size_t)EMB * EMB * 2;
  unsigned short* Wkb = (unsigned short*)p; p += (size_t)EMB * EMB * 2;
  unsigned short* Wvb = (unsigned short*)p; p += (size_t)EMB * EMB * 2;
  unsigned short* Wob = (unsigned short*)p; p += (size_t)EMB * EMB * 2;
  unsigned short* Qb  = (unsigned short*)p; p += (size_t)BZv * QL * EMB * 2;
  unsigned short* Kb  = (unsigned short*)p; p += (size_t)BZv * KVL * EMB * 2;
  unsigned short* Vb  = (unsigned short*)p; p += (size_t)BZv * KVL * EMB * 2;
  unsigned short* Cb  = (unsigned short*)p; p += (size_t)BZv * QL * EMB * 2;
  unsigned short* wbp = (unsigned short*)p; p += (size_t)BZv * KVL * 2;
  float* POp = (float*)p; p += (size_t)NSEG * NG * 1024 * 4;
  float* PMp = (float*)p; p += (size_t)NSEG * NG * 16 * 4;
  float* PDp = (float*)p; p += (size_t)NSEG * NG * 16 * 4;

  prep_kernel<<<1793, 256, 0, stream>>>(hid, Wq, Wk, Wv, Wo, kc, vc, mask,
                                        Xb, Wqb, Wkb, Wvb, Wob, Kb, Vb, kf, vf, wbp);
  qkv_gemm<<<dim3(48, 16), 256, 0, stream>>>(Xb, Wqb, Wkb, Wvb, bq, bk, bv, mask,
                                             Qb, Kb, Vb, kf, vf);
  attn_kernel<<<NSEG * 512, 256, 0, stream>>>(Qb, Kb, Vb, wbp, POp, PMp, PDp);
  attn_combine<<<512, 256, 0, stream>>>(POp, PMp, PDp, Cb);
  oproj_gemm<<<dim3(16, 32), 256, 0, stream>>>(Cb, Wob, bo, out_f);
}

// Round 11
// 245.684 us; speedup vs baseline: 1.0101x; 1.0101x over previous
//
#include <hip/hip_runtime.h>
#include <hip/hip_bf16.h>
#include <stdint.h>

#define BZv 4
#define QL 512
#define CL 1536
#define KVL 2048
#define EMB 1024
#define NH 16
#define HD 64
#define QSCALE 0.18033688011112042f  /* 0.125 * log2(e) */
#define NG 2048                       /* partial groups: 64 hb * 8 qt * 4 waves */

typedef __attribute__((ext_vector_type(8))) short short8;
typedef __attribute__((ext_vector_type(4))) float floatx4;
typedef __attribute__((ext_vector_type(4))) float fx4;

__device__ __forceinline__ unsigned short f2b(float f) {
  union { float f; unsigned int u; } v; v.f = f;
  return (unsigned short)((v.u + 0x7FFFu + ((v.u >> 16) & 1u)) >> 16);
}

__device__ __forceinline__ unsigned pku(float a, float b) {
  union { __hip_bfloat162 h; unsigned u; } c;
  c.h = __float22bfloat162_rn(make_float2(a, b));
  return c.u;   // low 16 = a, high 16 = b
}

__device__ __forceinline__ short8 cvt8(fx4 a, fx4 b) {
  short8 r;
  r[0] = (short)f2b(a.x); r[1] = (short)f2b(a.y);
  r[2] = (short)f2b(a.z); r[3] = (short)f2b(a.w);
  r[4] = (short)f2b(b.x); r[5] = (short)f2b(b.y);
  r[6] = (short)f2b(b.z); r[7] = (short)f2b(b.w);
  return r;
}
__device__ __forceinline__ short8 cvt8w(fx4 a, fx4 b, float w) {
  short8 r;
  r[0] = (short)f2b(a.x * w); r[1] = (short)f2b(a.y * w);
  r[2] = (short)f2b(a.z * w); r[3] = (short)f2b(a.w * w);
  r[4] = (short)f2b(b.x * w); r[5] = (short)f2b(b.y * w);
  r[6] = (short)f2b(b.z * w); r[7] = (short)f2b(b.w * w);
  return r;
}

#if __has_builtin(__builtin_amdgcn_exp2f)
#define EXP2F(x) __builtin_amdgcn_exp2f(x)
#else
#define EXP2F(x) exp2f(x)
#endif

__device__ __forceinline__ void gload_lds16(const void* g, void* l) {
  __builtin_amdgcn_global_load_lds(
      (const __attribute__((address_space(1))) unsigned char*)g,
      (__attribute__((address_space(3))) unsigned char*)l, 16, 0, 0);
}

#define BAR_LIGHT() asm volatile("s_barrier" ::: "memory")
#define BAR_K() asm volatile("s_waitcnt vmcnt(3) lgkmcnt(0)\n\ts_barrier" ::: "memory")

// ---------------- prep v4: hoisted loads (12 loads in flight/thread) ----------
__global__ __launch_bounds__(256) void prep_kernel(
    const float* __restrict__ hid, const float* __restrict__ Wq, const float* __restrict__ Wk,
    const float* __restrict__ Wv, const float* __restrict__ Wo,
    const float* __restrict__ kc, const float* __restrict__ vc, const float* __restrict__ msk,
    unsigned short* __restrict__ Xb, unsigned short* __restrict__ Wqb, unsigned short* __restrict__ Wkb,
    unsigned short* __restrict__ Wvb, unsigned short* __restrict__ Wob,
    unsigned short* __restrict__ Kb, unsigned short* __restrict__ Vb,
    float* __restrict__ kf, float* __restrict__ vf, unsigned short* __restrict__ wb)
{
  const int blk = blockIdx.x, tid = threadIdx.x;
  if (blk < 768) {
    const float* src; unsigned short* dst; int base;
    if (blk < 256) { src = hid; dst = Xb; base = blk * 2048; }
    else {
      int w = (blk - 256) >> 7, wo = (blk - 256) & 127;
      src = (w == 0) ? Wq : (w == 1) ? Wk : (w == 2) ? Wv : Wo;
      dst = (w == 0) ? Wqb : (w == 1) ? Wkb : (w == 2) ? Wvb : Wob;
      base = wo * 2048;
    }
    const fx4* s4 = (const fx4*)src;
    short8* d8 = (short8*)dst;
    fx4 v[8];
#pragma unroll
    for (int it = 0; it < 4; ++it) {
      int u = base + it * 512 + tid * 2;
      v[2 * it] = s4[u]; v[2 * it + 1] = s4[u + 1];
    }
#pragma unroll
    for (int it = 0; it < 4; ++it) {
      int u = base + it * 512 + tid * 2;
      d8[u >> 1] = cvt8(v[2 * it], v[2 * it + 1]);
    }
  } else if (blk < 1792) {
    const bool isV = blk >= 1280;
    const int r = blk - (isV ? 1280 : 768);
    const int bb = r >> 7, ko = r & 127;
    const fx4* s4 = (const fx4*)((isV ? vc : kc) + (long)bb * CL * EMB);
    fx4* f4 = (fx4*)((isV ? vf : kf) + (long)bb * KVL * EMB);
    short8* b8 = (short8*)((isV ? Vb : Kb) + (long)bb * KVL * EMB);
    const float* mrow = msk + bb * KVL;
    fx4 v[12];
#pragma unroll
    for (int it = 0; it < 6; ++it) {
      int u = ko * 3072 + it * 512 + tid * 2;
      v[2 * it] = s4[u]; v[2 * it + 1] = s4[u + 1];
    }
#pragma unroll
    for (int it = 0; it < 6; ++it) {
      int u = ko * 3072 + it * 512 + tid * 2;
      f4[u] = v[2 * it]; f4[u + 1] = v[2 * it + 1];
      if (isV) {
        float w = __expf(mrow[u >> 8]);   // u even: both halves share the row
        b8[u >> 1] = cvt8w(v[2 * it], v[2 * it + 1], w);
      } else {
        b8[u >> 1] = cvt8(v[2 * it], v[2 * it + 1]);
      }
    }
  } else {
    const fx4* m4 = (const fx4*)msk;
    short8* w8 = (short8*)wb;
#pragma unroll
    for (int it = 0; it < 4; ++it) {
      int u = it * 512 + tid * 2;
      fx4 a = m4[u], b = m4[u + 1];
      fx4 ea, eb;
      ea.x = __expf(a.x); ea.y = __expf(a.y); ea.z = __expf(a.z); ea.w = __expf(a.w);
      eb.x = __expf(b.x); eb.y = __expf(b.y); eb.z = __expf(b.z); eb.w = __expf(b.w);
      w8[u >> 1] = cvt8(ea, eb);
    }
  }
}

// ---------------- fused QKV GEMM v2: 128x64 tiles, BK=64, grid (48,16) --------
__global__ __launch_bounds__(256) void qkv_gemm(
    const unsigned short* __restrict__ Xb,
    const unsigned short* __restrict__ Wqb, const unsigned short* __restrict__ Wkb,
    const unsigned short* __restrict__ Wvb,
    const float* __restrict__ bq, const float* __restrict__ bk, const float* __restrict__ bv,
    const float* __restrict__ msk,
    unsigned short* __restrict__ Qb, unsigned short* __restrict__ Kb, unsigned short* __restrict__ Vb,
    float* __restrict__ kf, float* __restrict__ vf)
{
  __shared__ unsigned short At[128 * 64];   // row: 128B = 8 chunks of 16B, chunk-XOR swizzled
  __shared__ unsigned short Bt[64 * 64];
  const int tid = threadIdx.x, lane = tid & 63, wave = tid >> 6;
  const int quad = lane >> 4, l = lane & 15;
  const int sw = l & 7;
  const int mat = blockIdx.x >> 4;
  const int ncol = (blockIdx.x & 15) * 64;
  const int mbase = blockIdx.y * 128;
  const unsigned short* W = (mat == 0) ? Wqb : (mat == 1) ? Wkb : Wvb;
  const float* bias = (mat == 0) ? bq : (mat == 1) ? bk : bv;
  const int rh = wave * 32;

  floatx4 zero = {0.f, 0.f, 0.f, 0.f};
  floatx4 acc[2][4];
#pragma unroll
  for (int i = 0; i < 2; i++)
#pragma unroll
    for (int j = 0; j < 4; j++) acc[i][j] = zero;

  for (int k0 = 0; k0 < EMB; k0 += 64) {
    if (k0) BAR_LIGHT();
#pragma unroll
    for (int s = 0; s < 4; s++) {
      int g = s * 256 + tid;
      int r = g >> 3, c = g & 7;
      gload_lds16(Xb + (size_t)(mbase + r) * EMB + k0 + ((c ^ (r & 7)) * 8), &At[g * 8]);
    }
#pragma unroll
    for (int s = 0; s < 2; s++) {
      int g = s * 256 + tid;
      int r = g >> 3, c = g & 7;
      gload_lds16(W + (size_t)(ncol + r) * EMB + k0 + ((c ^ (r & 7)) * 8), &Bt[g * 8]);
    }
    __syncthreads();
    short8 af[2][2], bfr[4][2];
#pragma unroll
    for (int rt = 0; rt < 2; rt++) {
      const unsigned short* p = &At[(rh + rt * 16 + l) * 64];
      af[rt][0] = *(const short8*)&p[(quad ^ sw) * 8];
      af[rt][1] = *(const short8*)&p[((quad + 4) ^ sw) * 8];
    }
#pragma unroll
    for (int ct = 0; ct < 4; ct++) {
      const unsigned short* p = &Bt[(ct * 16 + l) * 64];
      bfr[ct][0] = *(const short8*)&p[(quad ^ sw) * 8];
      bfr[ct][1] = *(const short8*)&p[((quad + 4) ^ sw) * 8];
    }
#pragma unroll
    for (int rt = 0; rt < 2; rt++)
#pragma unroll
      for (int ct = 0; ct < 4; ct++) {
        acc[rt][ct] = __builtin_amdgcn_mfma_f32_16x16x32_bf16(af[rt][0], bfr[ct][0], acc[rt][ct], 0, 0, 0);
        acc[rt][ct] = __builtin_amdgcn_mfma_f32_16x16x32_bf16(af[rt][1], bfr[ct][1], acc[rt][ct], 0, 0, 0);
      }
  }

#pragma unroll
  for (int ct = 0; ct < 4; ct++) {
    int col = ncol + ct * 16 + l;
    float bb = bias[col];
#pragma unroll
    for (int rt = 0; rt < 2; rt++)
#pragma unroll
      for (int r = 0; r < 4; r++) {
        int m = mbase + rh + rt * 16 + quad * 4 + r;
        float val = acc[rt][ct][r] + bb;
        if (mat == 0) {
          Qb[(size_t)m * EMB + col] = f2b(val * QSCALE);
        } else {
          size_t a = ((size_t)(m >> 9) * KVL + CL + (m & 511)) * EMB + col;
          if (mat == 1) { Kb[a] = f2b(val); kf[a] = val; }
          else {
            float w = __expf(msk[(m >> 9) * KVL + CL + (m & 511)]);
            Vb[a] = f2b(val * w); vf[a] = val;
          }
        }
      }
  }
}

// ---------------- O-proj GEMM v2: 64x64 tiles, BK=64, grid (16,32) ------------
__global__ __launch_bounds__(256) void oproj_gemm(
    const unsigned short* __restrict__ A, const unsigned short* __restrict__ W,
    const float* __restrict__ bias, float* __restrict__ out)
{
  __shared__ unsigned short At[64 * 64];
  __shared__ unsigned short Bt[64 * 64];
  const int tid = threadIdx.x, lane = tid & 63, wave = tid >> 6;
  const int quad = lane >> 4, l = lane & 15;
  const int sw = l & 7;
  const int ncol = blockIdx.x * 64;
  const int mbase = blockIdx.y * 64;
  const int rh = (wave & 1) * 32, ch = (wave >> 1) * 32;

  floatx4 zero = {0.f, 0.f, 0.f, 0.f};
  floatx4 acc[2][2];
#pragma unroll
  for (int i = 0; i < 2; i++)
#pragma unroll
    for (int j = 0; j < 2; j++) acc[i][j] = zero;

  for (int k0 = 0; k0 < EMB; k0 += 64) {
    if (k0) BAR_LIGHT();
#pragma unroll
    for (int s = 0; s < 2; s++) {
      int g = s * 256 + tid;
      int r = g >> 3, c = g & 7;
      gload_lds16(A + (size_t)(mbase + r) * EMB + k0 + ((c ^ (r & 7)) * 8), &At[g * 8]);
      gload_lds16(W + (size_t)(ncol + r) * EMB + k0 + ((c ^ (r & 7)) * 8), &Bt[g * 8]);
    }
    __syncthreads();
    short8 af[2][2], bfr[2][2];
#pragma unroll
    for (int rt = 0; rt < 2; rt++) {
      const unsigned short* p = &At[(rh + rt * 16 + l) * 64];
      af[rt][0] = *(const short8*)&p[(quad ^ sw) * 8];
      af[rt][1] = *(const short8*)&p[((quad + 4) ^ sw) * 8];
    }
#pragma unroll
    for (int ct = 0; ct < 2; ct++) {
      const unsigned short* p = &Bt[(ch + ct * 16 + l) * 64];
      bfr[ct][0] = *(const short8*)&p[(quad ^ sw) * 8];
      bfr[ct][1] = *(const short8*)&p[((quad + 4) ^ sw) * 8];
    }
#pragma unroll
    for (int rt = 0; rt < 2; rt++)
#pragma unroll
      for (int ct = 0; ct < 2; ct++) {
        acc[rt][ct] = __builtin_amdgcn_mfma_f32_16x16x32_bf16(af[rt][0], bfr[ct][0], acc[rt][ct], 0, 0, 0);
        acc[rt][ct] = __builtin_amdgcn_mfma_f32_16x16x32_bf16(af[rt][1], bfr[ct][1], acc[rt][ct], 0, 0, 0);
      }
  }

#pragma unroll
  for (int ct = 0; ct < 2; ct++) {
    int col = ncol + ch + ct * 16 + l;
    float bb = bias[col];
#pragma unroll
    for (int rt = 0; rt < 2; rt++)
#pragma unroll
      for (int r = 0; r < 4; r++) {
        int m = mbase + rh + rt * 16 + quad * 4 + r;
        out[(size_t)m * EMB + col] = acc[rt][ct][r] + bb;
      }
  }
}

// ---------------- flash attention v10: split-KV x2 + in-register P exchange ---
// R8 structure (best total) with the Pl LDS round-trip replaced by 16 __shfl
// (mapping verified on-HW in R10: word w of pf0 = u[c=quad>>1][w&1] from lane
// 32*(quad&1)+l+16*(w>>1); pf1 same with c+2). LDS 25.7 KB.
__global__ __launch_bounds__(256, 4) void attn_kernel(
    const unsigned short* __restrict__ Qb, const unsigned short* __restrict__ Kb,
    const unsigned short* __restrict__ Vb, const unsigned short* __restrict__ wb,
    float* __restrict__ PO, float* __restrict__ PM, float* __restrict__ PD)
{
  __shared__ unsigned short Kt[2][64 * 64];   // linear rows (128B), swizzled chunks
  __shared__ unsigned short Vt[65 * 72];      // rows 0..63 = V^T[d][kv], row 64 = w[kv]

  const int bid = blockIdx.x;
  const int seg = bid >> 9;
  const int id = bid & 511;
  const int hb = id & 63, qt = id >> 6;
  const int b = hb >> 4, h = hb & 15;
  const int tid = threadIdx.x, lane = tid & 63, wave = tid >> 6;
  const int quad = lane >> 4, l = lane & 15;
  const int qbase = qt * 64 + wave * 16;

  const int nt_tot = (CL >> 6) + qt + 1;      // 25..32 tiles of 64 kv
  const int n0 = nt_tot >> 1;
  const int t_beg = seg ? n0 : 0;
  const int t_end = seg ? nt_tot : n0;

  const unsigned short* qp = Qb + (size_t)(b * QL + qbase + l) * EMB + h * HD + quad * 8;
  const short8 bq0 = *(const short8*)qp;
  const short8 bq1 = *(const short8*)(qp + 32);

  floatx4 zero = {0.f, 0.f, 0.f, 0.f};
  floatx4 o[4], o4 = zero;
#pragma unroll
  for (int c = 0; c < 4; c++) o[c] = zero;
  float mr = -INFINITY;                        // per-lane state for q = l

  const int vp = tid & 31, vg = tid >> 5;
  const unsigned short* vsrc = Vb + (size_t)(b * KVL) * EMB + h * HD + vg * 8;
  const unsigned short* wsrc = wb + (size_t)b * KVL + 2 * vp;
  const unsigned short* ksrc = Kb + (size_t)(b * KVL) * EMB + h * HD;
  const int sw = l & 7;                        // read-side chunk XOR

  uint4 va, vbr; ushort2 wn;
  auto VLOAD = [&](int t) {
    const unsigned short* vs = vsrc + (size_t)(t * 64 + 2 * vp) * EMB;
    va = *(const uint4*)vs;
    vbr = *(const uint4*)(vs + EMB);
    wn = *(const ushort2*)(wsrc + t * 64);   // uniform: every wave issues 3 V loads
  };
  auto VSTAGE = [&]() {
    const unsigned short* pa = (const unsigned short*)&va;
    const unsigned short* pb = (const unsigned short*)&vbr;
#pragma unroll
    for (int j = 0; j < 8; j++) {
      ushort2 tt; tt.x = pa[j]; tt.y = pb[j];
      *(ushort2*)&Vt[(vg * 8 + j) * 72 + 2 * vp] = tt;
    }
    if (vg == 0) *(ushort2*)&Vt[64 * 72 + 2 * vp] = wn;
  };
  auto GLOAD_K = [&](int t, int buf) {
    const int kv0 = t * 64;
#pragma unroll
    for (int s = 0; s < 2; s++) {
      int g = s * 256 + tid;
      int r = g >> 3, k = g & 7;
      gload_lds16(ksrc + (size_t)(kv0 + r) * EMB + ((k ^ (r & 7)) * 8),
                  &Kt[buf][g * 8]);
    }
  };

  // prologue (full drains; one-time cost)
  VLOAD(t_beg);
  GLOAD_K(t_beg, 0);
  __syncthreads();
  VSTAGE();
  if (t_beg + 1 < t_end) VLOAD(t_beg + 1);
  __syncthreads();

  const int la = 32 * (quad & 1) + l;          // P-exchange source lane
  const bool chi = (quad & 2) != 0;

  int cur = 0;
  for (int t = t_beg; t < t_end; ++t) {
    if (t + 1 < t_end) GLOAD_K(t + 1, cur ^ 1);   // oldest vmem: 2 gload_lds
    const int kv0 = t * 64;
    floatx4 s[4];
#pragma unroll
    for (int c = 0; c < 4; c++) {
      const int rr = c * 16 + l;
      const unsigned short* krow = &Kt[cur][rr * 64];
      short8 k0 = *(const short8*)&krow[(quad ^ sw) * 8];
      short8 k1 = *(const short8*)&krow[((quad + 4) ^ sw) * 8];
      s[c] = __builtin_amdgcn_mfma_f32_16x16x32_bf16(k0, bq0, zero, 0, 0, 0);
      s[c] = __builtin_amdgcn_mfma_f32_16x16x32_bf16(k1, bq1, s[c], 0, 0, 0);
    }
    if (kv0 + 63 > CL + qbase) {
      const int lim = CL + qbase + l;
#pragma unroll
      for (int c = 0; c < 4; c++) {
        int kvb = kv0 + c * 16 + quad * 4;
#pragma unroll
        for (int r = 0; r < 4; r++)
          s[c][r] = (kvb + r <= lim) ? s[c][r] : -INFINITY;
      }
    }
    float u0 = fmaxf(fmaxf(s[0][0], s[0][1]), fmaxf(s[0][2], s[0][3]));
    float u1 = fmaxf(fmaxf(s[1][0], s[1][1]), fmaxf(s[1][2], s[1][3]));
    float u2 = fmaxf(fmaxf(s[2][0], s[2][1]), fmaxf(s[2][2], s[2][3]));
    float u3 = fmaxf(fmaxf(s[3][0], s[3][1]), fmaxf(s[3][2], s[3][3]));
    float lmax = fmaxf(fmaxf(u0, u1), fmaxf(u2, u3));
    lmax = fmaxf(lmax, __shfl_xor(lmax, 16, 64));
    lmax = fmaxf(lmax, __shfl_xor(lmax, 32, 64));
    float mnew = fmaxf(mr, lmax);
    float alpha = EXP2F(mr - mnew);
    mr = mnew;
    // P~ = exp2(s - mnew) packed to bf16 pairs (plo = kv pair r0,r1; phi = r2,r3)
    unsigned plo[4], phi[4];
#pragma unroll
    for (int c = 0; c < 4; c++) {
      float p0 = EXP2F(s[c][0] - mnew), p1 = EXP2F(s[c][1] - mnew);
      float p2 = EXP2F(s[c][2] - mnew), p3 = EXP2F(s[c][3] - mnew);
      plo[c] = pku(p0, p1); phi[c] = pku(p2, p3);
    }
#pragma unroll
    for (int c = 0; c < 4; c++)
#pragma unroll
      for (int r = 0; r < 4; r++) o[c][r] *= alpha;
#pragma unroll
    for (int r = 0; r < 4; r++) o4[r] *= alpha;
    // in-register exchange: 16 shfl + 8 selects (replaces Pl LDS round-trip)
    unsigned a0 = (unsigned)__shfl((int)plo[0], la), a1 = (unsigned)__shfl((int)plo[1], la);
    unsigned b0 = (unsigned)__shfl((int)phi[0], la), b1 = (unsigned)__shfl((int)phi[1], la);
    unsigned c0 = (unsigned)__shfl((int)plo[0], la + 16), c1 = (unsigned)__shfl((int)plo[1], la + 16);
    unsigned d0 = (unsigned)__shfl((int)phi[0], la + 16), d1 = (unsigned)__shfl((int)phi[1], la + 16);
    unsigned e0 = (unsigned)__shfl((int)plo[2], la), e1 = (unsigned)__shfl((int)plo[3], la);
    unsigned f0 = (unsigned)__shfl((int)phi[2], la), f1 = (unsigned)__shfl((int)phi[3], la);
    unsigned g0 = (unsigned)__shfl((int)plo[2], la + 16), g1 = (unsigned)__shfl((int)plo[3], la + 16);
    unsigned h0 = (unsigned)__shfl((int)phi[2], la + 16), h1 = (unsigned)__shfl((int)phi[3], la + 16);
    union { unsigned u[4]; short8 s8; } P0, P1;
    P0.u[0] = chi ? a1 : a0;  P0.u[1] = chi ? b1 : b0;
    P0.u[2] = chi ? c1 : c0;  P0.u[3] = chi ? d1 : d0;
    P1.u[0] = chi ? e1 : e0;  P1.u[1] = chi ? f1 : f0;
    P1.u[2] = chi ? g1 : g0;  P1.u[3] = chi ? h1 : h0;
    short8 pf0 = P0.s8, pf1 = P1.s8;
    short8 vw0 = *(const short8*)&Vt[64 * 72 + quad * 8];
    short8 vw1 = *(const short8*)&Vt[64 * 72 + 32 + quad * 8];
    o4 = __builtin_amdgcn_mfma_f32_16x16x32_bf16(vw0, pf0, o4, 0, 0, 0);
    o4 = __builtin_amdgcn_mfma_f32_16x16x32_bf16(vw1, pf1, o4, 0, 0, 0);
#pragma unroll
    for (int c = 0; c < 4; c++) {
      short8 a0v = *(const short8*)&Vt[(c * 16 + l) * 72 + quad * 8];
      short8 a1v = *(const short8*)&Vt[(c * 16 + l) * 72 + 32 + quad * 8];
      o[c] = __builtin_amdgcn_mfma_f32_16x16x32_bf16(a0v, pf0, o[c], 0, 0, 0);
      o[c] = __builtin_amdgcn_mfma_f32_16x16x32_bf16(a1v, pf1, o[c], 0, 0, 0);
    }
    BAR_LIGHT();                   // barrier1: Vt reads done (exec order); no drain
    if (t + 1 < t_end) {
      VSTAGE();
      if (t + 2 < t_end) VLOAD(t + 2);
    }
    BAR_K();                       // barrier2: drain K gloads + ds_writes only
    cur ^= 1;
  }

  // epilogue: store partials (nontemporal; single-use stream)
  const int gid = hb * 32 + qt * 4 + wave;
  float* po = PO + ((size_t)(seg * NG + gid)) * 1024 + l * 64;
#pragma unroll
  for (int c = 0; c < 4; c++)
    __builtin_nontemporal_store(o[c], (floatx4*)&po[c * 16 + quad * 4]);
  if (quad == 0) {
    __builtin_nontemporal_store(mr, &PM[(size_t)(seg * NG + gid) * 16 + l]);
    __builtin_nontemporal_store(o4[0], &PD[(size_t)(seg * NG + gid) * 16 + l]);
  }
}

// ---------------- combine the 2 KV-split partials -> Cb (bf16) ----------------
__global__ __launch_bounds__(256) void attn_combine(
    const float* __restrict__ PO, const float* __restrict__ PM, const float* __restrict__ PD,
    unsigned short* __restrict__ Cb)
{
  const int tid = threadIdx.x, wave = tid >> 6, lane = tid & 63;
  const int quad = lane >> 4, l = lane & 15;
  const int gid = blockIdx.x * 4 + wave;       // 0..2047
  const int hb = gid >> 5, qt = (gid >> 2) & 7, wv = gid & 3;
  const int b = hb >> 4, h = hb & 15;
  const int q = qt * 64 + wv * 16 + l;

  float m0 = __builtin_nontemporal_load(&PM[(size_t)gid * 16 + l]);
  float m1 = __builtin_nontemporal_load(&PM[(size_t)(NG + gid) * 16 + l]);
  float d0 = __builtin_nontemporal_load(&PD[(size_t)gid * 16 + l]);
  float d1 = __builtin_nontemporal_load(&PD[(size_t)(NG + gid) * 16 + l]);
  float M = fmaxf(m0, m1);
  float a0 = EXP2F(m0 - M), a1 = EXP2F(m1 - M);
  float inv = 1.0f / (d0 * a0 + d1 * a1);
  a0 *= inv; a1 *= inv;

  const fx4* p0 = (const fx4*)(PO + (size_t)gid * 1024 + l * 64 + quad * 16);
  const fx4* p1 = (const fx4*)((const float*)p0 + (size_t)NG * 1024);
  unsigned short* cp = Cb + (size_t)(b * QL + q) * EMB + h * HD + quad * 16;
#pragma unroll
  for (int v = 0; v < 4; v++) {
    fx4 x0 = __builtin_nontemporal_load(p0 + v);
    fx4 x1 = __builtin_nontemporal_load(p1 + v);
    ushort4 w4;
    w4.x = f2b(x0.x * a0 + x1.x * a1);
    w4.y = f2b(x0.y * a0 + x1.y * a1);
    w4.z = f2b(x0.z * a0 + x1.z * a1);
    w4.w = f2b(x0.w * a0 + x1.w * a1);
    *(ushort4*)(cp + v * 4) = w4;
  }
}

extern "C" void kernel_launch(void* const* d_in, const int* in_sizes, int n_in,
                              void* d_out, int out_size, void* d_ws, size_t ws_size,
                              hipStream_t stream) {
  const float* hid  = (const float*)d_in[0];
  const float* mask = (const float*)d_in[1];
  const float* kc   = (const float*)d_in[2];
  const float* vc   = (const float*)d_in[3];
  const float* Wq   = (const float*)d_in[4];
  const float* bq   = (const float*)d_in[5];
  const float* Wk   = (const float*)d_in[6];
  const float* bk   = (const float*)d_in[7];
  const float* Wv   = (const float*)d_in[8];
  const float* bv   = (const float*)d_in[9];
  const float* Wo   = (const float*)d_in[10];
  const float* bo   = (const float*)d_in[11];

  float* out_f = (float*)d_out;
  float* kf = out_f + (size_t)BZv * QL * EMB;
  float* vf = kf + (size_t)BZv * KVL * EMB;

  char* p = (char*)d_ws;
  unsigned short* Xb  = (unsigned short*)p; p += (size_t)BZv * QL * EMB * 2;
  unsigned short* Wqb = (unsigned short*)p; p += (size_t)EMB * EMB * 2;
  unsigned short* Wkb = (unsigned short*)p; p += (size_t)EMB * EMB * 2;
  unsigned short* Wvb = (unsigned short*)p; p += (size_t)EMB * EMB * 2;
  unsigned short* Wob = (unsigned short*)p; p += (size_t)EMB * EMB * 2;
  unsigned short* Qb  = (unsigned short*)p; p += (size_t)BZv * QL * EMB * 2;
  unsigned short* Kb  = (unsigned short*)p; p += (size_t)BZv * KVL * EMB * 2;
  unsigned short* Vb  = (unsigned short*)p; p += (size_t)BZv * KVL * EMB * 2;
  unsigned short* Cb  = (unsigned short*)p; p += (size_t)BZv * QL * EMB * 2;
  unsigned short* wbp = (unsigned short*)p; p += (size_t)BZv * KVL * 2;
  float* POp = (float*)p; p += (size_t)2 * NG * 1024 * 4;
  float* PMp = (float*)p; p += (size_t)2 * NG * 16 * 4;
  float* PDp = (float*)p; p += (size_t)2 * NG * 16 * 4;

  prep_kernel<<<1793, 256, 0, stream>>>(hid, Wq, Wk, Wv, Wo, kc, vc, mask,
                                        Xb, Wqb, Wkb, Wvb, Wob, Kb, Vb, kf, vf, wbp);
  qkv_gemm<<<dim3(48, 16), 256, 0, stream>>>(Xb, Wqb, Wkb, Wvb, bq, bk, bv, mask,
                                             Qb, Kb, Vb, kf, vf);
  attn_kernel<<<1024, 256, 0, stream>>>(Qb, Kb, Vb, wbp, POp, PMp, PDp);
  attn_combine<<<512, 256, 0, stream>>>(POp, PMp, PDp, Cb);
  oproj_gemm<<<dim3(16, 32), 256, 0, stream>>>(Cb, Wob, bo, out_f);
}

// Round 12
// 235.121 us; speedup vs baseline: 1.0555x; 1.0449x over previous
//
#include <hip/hip_runtime.h>
#include <hip/hip_bf16.h>
#include <stdint.h>

#define BZv 4
#define QL 512
#define CL 1536
#define KVL 2048
#define EMB 1024
#define NH 16
#define HD 64
#define QSCALE 0.18033688011112042f  /* 0.125 * log2(e) */
#define NG 2048                       /* partial groups: 64 hb * 8 qt * 4 waves */

typedef __attribute__((ext_vector_type(8))) short short8;
typedef __attribute__((ext_vector_type(4))) float floatx4;
typedef __attribute__((ext_vector_type(4))) float fx4;

__device__ __forceinline__ unsigned short f2b(float f) {
  union { float f; unsigned int u; } v; v.f = f;
  return (unsigned short)((v.u + 0x7FFFu + ((v.u >> 16) & 1u)) >> 16);
}

__device__ __forceinline__ ushort2 pk2(float a, float b) {
  union { __hip_bfloat162 h; ushort2 u; } c;
  c.h = __float22bfloat162_rn(make_float2(a, b));
  return c.u;
}

__device__ __forceinline__ short8 cvt8(fx4 a, fx4 b) {
  short8 r;
  r[0] = (short)f2b(a.x); r[1] = (short)f2b(a.y);
  r[2] = (short)f2b(a.z); r[3] = (short)f2b(a.w);
  r[4] = (short)f2b(b.x); r[5] = (short)f2b(b.y);
  r[6] = (short)f2b(b.z); r[7] = (short)f2b(b.w);
  return r;
}
__device__ __forceinline__ short8 cvt8w(fx4 a, fx4 b, float w) {
  short8 r;
  r[0] = (short)f2b(a.x * w); r[1] = (short)f2b(a.y * w);
  r[2] = (short)f2b(a.z * w); r[3] = (short)f2b(a.w * w);
  r[4] = (short)f2b(b.x * w); r[5] = (short)f2b(b.y * w);
  r[6] = (short)f2b(b.z * w); r[7] = (short)f2b(b.w * w);
  return r;
}

#if __has_builtin(__builtin_amdgcn_exp2f)
#define EXP2F(x) __builtin_amdgcn_exp2f(x)
#else
#define EXP2F(x) exp2f(x)
#endif

__device__ __forceinline__ void gload_lds16(const void* g, void* l) {
  __builtin_amdgcn_global_load_lds(
      (const __attribute__((address_space(1))) unsigned char*)g,
      (__attribute__((address_space(3))) unsigned char*)l, 16, 0, 0);
}

// ---------------- prep v4: hoisted loads (12 loads in flight/thread) ----------
__global__ __launch_bounds__(256) void prep_kernel(
    const float* __restrict__ hid, const float* __restrict__ Wq, const float* __restrict__ Wk,
    const float* __restrict__ Wv, const float* __restrict__ Wo,
    const float* __restrict__ kc, const float* __restrict__ vc, const float* __restrict__ msk,
    unsigned short* __restrict__ Xb, unsigned short* __restrict__ Wqb, unsigned short* __restrict__ Wkb,
    unsigned short* __restrict__ Wvb, unsigned short* __restrict__ Wob,
    unsigned short* __restrict__ Kb, unsigned short* __restrict__ Vb,
    float* __restrict__ kf, float* __restrict__ vf, unsigned short* __restrict__ wb)
{
  const int blk = blockIdx.x, tid = threadIdx.x;
  if (blk < 768) {
    const float* src; unsigned short* dst; int base;
    if (blk < 256) { src = hid; dst = Xb; base = blk * 2048; }
    else {
      int w = (blk - 256) >> 7, wo = (blk - 256) & 127;
      src = (w == 0) ? Wq : (w == 1) ? Wk : (w == 2) ? Wv : Wo;
      dst = (w == 0) ? Wqb : (w == 1) ? Wkb : (w == 2) ? Wvb : Wob;
      base = wo * 2048;
    }
    const fx4* s4 = (const fx4*)src;
    short8* d8 = (short8*)dst;
    fx4 v[8];
#pragma unroll
    for (int it = 0; it < 4; ++it) {
      int u = base + it * 512 + tid * 2;
      v[2 * it] = s4[u]; v[2 * it + 1] = s4[u + 1];
    }
#pragma unroll
    for (int it = 0; it < 4; ++it) {
      int u = base + it * 512 + tid * 2;
      d8[u >> 1] = cvt8(v[2 * it], v[2 * it + 1]);
    }
  } else if (blk < 1792) {
    const bool isV = blk >= 1280;
    const int r = blk - (isV ? 1280 : 768);
    const int bb = r >> 7, ko = r & 127;
    const fx4* s4 = (const fx4*)((isV ? vc : kc) + (long)bb * CL * EMB);
    fx4* f4 = (fx4*)((isV ? vf : kf) + (long)bb * KVL * EMB);
    short8* b8 = (short8*)((isV ? Vb : Kb) + (long)bb * KVL * EMB);
    const float* mrow = msk + bb * KVL;
    fx4 v[12];
#pragma unroll
    for (int it = 0; it < 6; ++it) {
      int u = ko * 3072 + it * 512 + tid * 2;
      v[2 * it] = s4[u]; v[2 * it + 1] = s4[u + 1];
    }
#pragma unroll
    for (int it = 0; it < 6; ++it) {
      int u = ko * 3072 + it * 512 + tid * 2;
      f4[u] = v[2 * it]; f4[u + 1] = v[2 * it + 1];
      if (isV) {
        float w = __expf(mrow[u >> 8]);   // u even: both halves share the row
        b8[u >> 1] = cvt8w(v[2 * it], v[2 * it + 1], w);
      } else {
        b8[u >> 1] = cvt8(v[2 * it], v[2 * it + 1]);
      }
    }
  } else {
    const fx4* m4 = (const fx4*)msk;
    short8* w8 = (short8*)wb;
#pragma unroll
    for (int it = 0; it < 4; ++it) {
      int u = it * 512 + tid * 2;
      fx4 a = m4[u], b = m4[u + 1];
      fx4 ea, eb;
      ea.x = __expf(a.x); ea.y = __expf(a.y); ea.z = __expf(a.z); ea.w = __expf(a.w);
      eb.x = __expf(b.x); eb.y = __expf(b.y); eb.z = __expf(b.z); eb.w = __expf(b.w);
      w8[u >> 1] = cvt8(ea, eb);
    }
  }
}

// ---------------- fused QKV GEMM v2: 128x64 tiles, BK=64, grid (48,16) --------
__global__ __launch_bounds__(256) void qkv_gemm(
    const unsigned short* __restrict__ Xb,
    const unsigned short* __restrict__ Wqb, const unsigned short* __restrict__ Wkb,
    const unsigned short* __restrict__ Wvb,
    const float* __restrict__ bq, const float* __restrict__ bk, const float* __restrict__ bv,
    const float* __restrict__ msk,
    unsigned short* __restrict__ Qb, unsigned short* __restrict__ Kb, unsigned short* __restrict__ Vb,
    float* __restrict__ kf, float* __restrict__ vf)
{
  __shared__ unsigned short At[128 * 64];   // row: 128B = 8 chunks of 16B, chunk-XOR swizzled
  __shared__ unsigned short Bt[64 * 64];
  const int tid = threadIdx.x, lane = tid & 63, wave = tid >> 6;
  const int quad = lane >> 4, l = lane & 15;
  const int sw = l & 7;
  const int mat = blockIdx.x >> 4;
  const int ncol = (blockIdx.x & 15) * 64;
  const int mbase = blockIdx.y * 128;
  const unsigned short* W = (mat == 0) ? Wqb : (mat == 1) ? Wkb : Wvb;
  const float* bias = (mat == 0) ? bq : (mat == 1) ? bk : bv;
  const int rh = wave * 32;

  floatx4 zero = {0.f, 0.f, 0.f, 0.f};
  floatx4 acc[2][4];
#pragma unroll
  for (int i = 0; i < 2; i++)
#pragma unroll
    for (int j = 0; j < 4; j++) acc[i][j] = zero;

  for (int k0 = 0; k0 < EMB; k0 += 64) {
    __syncthreads();
#pragma unroll
    for (int s = 0; s < 4; s++) {
      int g = s * 256 + tid;
      int r = g >> 3, c = g & 7;
      gload_lds16(Xb + (size_t)(mbase + r) * EMB + k0 + ((c ^ (r & 7)) * 8), &At[g * 8]);
    }
#pragma unroll
    for (int s = 0; s < 2; s++) {
      int g = s * 256 + tid;
      int r = g >> 3, c = g & 7;
      gload_lds16(W + (size_t)(ncol + r) * EMB + k0 + ((c ^ (r & 7)) * 8), &Bt[g * 8]);
    }
    __syncthreads();
    short8 af[2][2], bfr[4][2];
#pragma unroll
    for (int rt = 0; rt < 2; rt++) {
      const unsigned short* p = &At[(rh + rt * 16 + l) * 64];
      af[rt][0] = *(const short8*)&p[(quad ^ sw) * 8];
      af[rt][1] = *(const short8*)&p[((quad + 4) ^ sw) * 8];
    }
#pragma unroll
    for (int ct = 0; ct < 4; ct++) {
      const unsigned short* p = &Bt[(ct * 16 + l) * 64];
      bfr[ct][0] = *(const short8*)&p[(quad ^ sw) * 8];
      bfr[ct][1] = *(const short8*)&p[((quad + 4) ^ sw) * 8];
    }
#pragma unroll
    for (int rt = 0; rt < 2; rt++)
#pragma unroll
      for (int ct = 0; ct < 4; ct++) {
        acc[rt][ct] = __builtin_amdgcn_mfma_f32_16x16x32_bf16(af[rt][0], bfr[ct][0], acc[rt][ct], 0, 0, 0);
        acc[rt][ct] = __builtin_amdgcn_mfma_f32_16x16x32_bf16(af[rt][1], bfr[ct][1], acc[rt][ct], 0, 0, 0);
      }
  }

#pragma unroll
  for (int ct = 0; ct < 4; ct++) {
    int col = ncol + ct * 16 + l;
    float bb = bias[col];
#pragma unroll
    for (int rt = 0; rt < 2; rt++)
#pragma unroll
      for (int r = 0; r < 4; r++) {
        int m = mbase + rh + rt * 16 + quad * 4 + r;
        float val = acc[rt][ct][r] + bb;
        if (mat == 0) {
          Qb[(size_t)m * EMB + col] = f2b(val * QSCALE);
        } else {
          size_t a = ((size_t)(m >> 9) * KVL + CL + (m & 511)) * EMB + col;
          if (mat == 1) { Kb[a] = f2b(val); kf[a] = val; }
          else {
            float w = __expf(msk[(m >> 9) * KVL + CL + (m & 511)]);
            Vb[a] = f2b(val * w); vf[a] = val;
          }
        }
      }
  }
}

// ---------------- O-proj GEMM v2: 64x64 tiles, BK=64, grid (16,32) ------------
__global__ __launch_bounds__(256) void oproj_gemm(
    const unsigned short* __restrict__ A, const unsigned short* __restrict__ W,
    const float* __restrict__ bias, float* __restrict__ out)
{
  __shared__ unsigned short At[64 * 64];
  __shared__ unsigned short Bt[64 * 64];
  const int tid = threadIdx.x, lane = tid & 63, wave = tid >> 6;
  const int quad = lane >> 4, l = lane & 15;
  const int sw = l & 7;
  const int ncol = blockIdx.x * 64;
  const int mbase = blockIdx.y * 64;
  const int rh = (wave & 1) * 32, ch = (wave >> 1) * 32;

  floatx4 zero = {0.f, 0.f, 0.f, 0.f};
  floatx4 acc[2][2];
#pragma unroll
  for (int i = 0; i < 2; i++)
#pragma unroll
    for (int j = 0; j < 2; j++) acc[i][j] = zero;

  for (int k0 = 0; k0 < EMB; k0 += 64) {
    __syncthreads();
#pragma unroll
    for (int s = 0; s < 2; s++) {
      int g = s * 256 + tid;
      int r = g >> 3, c = g & 7;
      gload_lds16(A + (size_t)(mbase + r) * EMB + k0 + ((c ^ (r & 7)) * 8), &At[g * 8]);
      gload_lds16(W + (size_t)(ncol + r) * EMB + k0 + ((c ^ (r & 7)) * 8), &Bt[g * 8]);
    }
    __syncthreads();
    short8 af[2][2], bfr[2][2];
#pragma unroll
    for (int rt = 0; rt < 2; rt++) {
      const unsigned short* p = &At[(rh + rt * 16 + l) * 64];
      af[rt][0] = *(const short8*)&p[(quad ^ sw) * 8];
      af[rt][1] = *(const short8*)&p[((quad + 4) ^ sw) * 8];
    }
#pragma unroll
    for (int ct = 0; ct < 2; ct++) {
      const unsigned short* p = &Bt[(ch + ct * 16 + l) * 64];
      bfr[ct][0] = *(const short8*)&p[(quad ^ sw) * 8];
      bfr[ct][1] = *(const short8*)&p[((quad + 4) ^ sw) * 8];
    }
#pragma unroll
    for (int rt = 0; rt < 2; rt++)
#pragma unroll
      for (int ct = 0; ct < 2; ct++) {
        acc[rt][ct] = __builtin_amdgcn_mfma_f32_16x16x32_bf16(af[rt][0], bfr[ct][0], acc[rt][ct], 0, 0, 0);
        acc[rt][ct] = __builtin_amdgcn_mfma_f32_16x16x32_bf16(af[rt][1], bfr[ct][1], acc[rt][ct], 0, 0, 0);
      }
  }

#pragma unroll
  for (int ct = 0; ct < 2; ct++) {
    int col = ncol + ch + ct * 16 + l;
    float bb = bias[col];
#pragma unroll
    for (int rt = 0; rt < 2; rt++)
#pragma unroll
      for (int r = 0; r < 4; r++) {
        int m = mbase + rh + rt * 16 + quad * 4 + r;
        out[(size_t)m * EMB + col] = acc[rt][ct][r] + bb;
      }
  }
}

// ---------------- flash attention v4 (measured best): split-KV x2 -------------
__global__ __launch_bounds__(256, 4) void attn_kernel(
    const unsigned short* __restrict__ Qb, const unsigned short* __restrict__ Kb,
    const unsigned short* __restrict__ Vb, const unsigned short* __restrict__ wb,
    float* __restrict__ PO, float* __restrict__ PM, float* __restrict__ PD)
{
  __shared__ unsigned short Kt[2][64 * 64];   // linear rows (128B), swizzled chunks
  __shared__ unsigned short Vt[65 * 72];      // rows 0..63 = V^T[d][kv], row 64 = w[kv]
  __shared__ unsigned short Pl[4][16 * 72];   // per-wave P~ [q][kv]

  const int bid = blockIdx.x;
  const int seg = bid >> 9;
  const int id = bid & 511;
  const int hb = id & 63, qt = id >> 6;
  const int b = hb >> 4, h = hb & 15;
  const int tid = threadIdx.x, lane = tid & 63, wave = tid >> 6;
  const int quad = lane >> 4, l = lane & 15;
  const int qbase = qt * 64 + wave * 16;

  const int nt_tot = (CL >> 6) + qt + 1;      // 25..32 tiles of 64 kv
  const int n0 = nt_tot >> 1;
  const int t_beg = seg ? n0 : 0;
  const int t_end = seg ? nt_tot : n0;

  const unsigned short* qp = Qb + (size_t)(b * QL + qbase + l) * EMB + h * HD + quad * 8;
  const short8 bq0 = *(const short8*)qp;
  const short8 bq1 = *(const short8*)(qp + 32);

  floatx4 zero = {0.f, 0.f, 0.f, 0.f};
  floatx4 o[4], o4 = zero;
#pragma unroll
  for (int c = 0; c < 4; c++) o[c] = zero;
  float mr = -INFINITY;                        // per-lane state for q = l

  const int vp = tid & 31, vg = tid >> 5;
  const unsigned short* vsrc = Vb + (size_t)(b * KVL) * EMB + h * HD + vg * 8;
  const unsigned short* wsrc = wb + (size_t)b * KVL + 2 * vp;
  const unsigned short* ksrc = Kb + (size_t)(b * KVL) * EMB + h * HD;
  const int sw = l & 7;                        // read-side chunk XOR

  uint4 va, vbr; ushort2 wn;
  auto VLOAD = [&](int t) {
    const unsigned short* vs = vsrc + (size_t)(t * 64 + 2 * vp) * EMB;
    va = *(const uint4*)vs;
    vbr = *(const uint4*)(vs + EMB);
    if (vg == 0) wn = *(const ushort2*)(wsrc + t * 64);
  };
  auto VSTAGE = [&]() {
    const unsigned short* pa = (const unsigned short*)&va;
    const unsigned short* pb = (const unsigned short*)&vbr;
#pragma unroll
    for (int j = 0; j < 8; j++) {
      ushort2 tt; tt.x = pa[j]; tt.y = pb[j];
      *(ushort2*)&Vt[(vg * 8 + j) * 72 + 2 * vp] = tt;
    }
    if (vg == 0) *(ushort2*)&Vt[64 * 72 + 2 * vp] = wn;
  };
  auto GLOAD_K = [&](int t, int buf) {
    const int kv0 = t * 64;
#pragma unroll
    for (int s = 0; s < 2; s++) {
      int g = s * 256 + tid;
      int r = g >> 3, k = g & 7;
      gload_lds16(ksrc + (size_t)(kv0 + r) * EMB + ((k ^ (r & 7)) * 8),
                  &Kt[buf][g * 8]);
    }
  };

  // prologue
  VLOAD(t_beg);
  GLOAD_K(t_beg, 0);
  __syncthreads();
  VSTAGE();
  if (t_beg + 1 < t_end) VLOAD(t_beg + 1);
  __syncthreads();

  int cur = 0;
  for (int t = t_beg; t < t_end; ++t) {
    if (t + 1 < t_end) GLOAD_K(t + 1, cur ^ 1);   // prefetch under compute
    const int kv0 = t * 64;
    floatx4 s[4];
#pragma unroll
    for (int c = 0; c < 4; c++) {
      const int rr = c * 16 + l;
      const unsigned short* krow = &Kt[cur][rr * 64];
      short8 k0 = *(const short8*)&krow[(quad ^ sw) * 8];
      short8 k1 = *(const short8*)&krow[((quad + 4) ^ sw) * 8];
      s[c] = __builtin_amdgcn_mfma_f32_16x16x32_bf16(k0, bq0, zero, 0, 0, 0);
      s[c] = __builtin_amdgcn_mfma_f32_16x16x32_bf16(k1, bq1, s[c], 0, 0, 0);
    }
    if (kv0 + 63 > CL + qbase) {
      const int lim = CL + qbase + l;
#pragma unroll
      for (int c = 0; c < 4; c++) {
        int kvb = kv0 + c * 16 + quad * 4;
#pragma unroll
        for (int r = 0; r < 4; r++)
          s[c][r] = (kvb + r <= lim) ? s[c][r] : -INFINITY;
      }
    }
    float u0 = fmaxf(fmaxf(s[0][0], s[0][1]), fmaxf(s[0][2], s[0][3]));
    float u1 = fmaxf(fmaxf(s[1][0], s[1][1]), fmaxf(s[1][2], s[1][3]));
    float u2 = fmaxf(fmaxf(s[2][0], s[2][1]), fmaxf(s[2][2], s[2][3]));
    float u3 = fmaxf(fmaxf(s[3][0], s[3][1]), fmaxf(s[3][2], s[3][3]));
    float lmax = fmaxf(fmaxf(u0, u1), fmaxf(u2, u3));
    lmax = fmaxf(lmax, __shfl_xor(lmax, 16, 64));
    lmax = fmaxf(lmax, __shfl_xor(lmax, 32, 64));
    float mnew = fmaxf(mr, lmax);
    float alpha = EXP2F(mr - mnew);
    mr = mnew;
#pragma unroll
    for (int c = 0; c < 4; c++) {
      float p0 = EXP2F(s[c][0] - mnew), p1 = EXP2F(s[c][1] - mnew);
      float p2 = EXP2F(s[c][2] - mnew), p3 = EXP2F(s[c][3] - mnew);
      ushort2 lo = pk2(p0, p1), hi = pk2(p2, p3);
      ushort4 pk; pk.x = lo.x; pk.y = lo.y; pk.z = hi.x; pk.w = hi.y;
      *(ushort4*)&Pl[wave][l * 72 + c * 16 + quad * 4] = pk;
    }
#pragma unroll
    for (int c = 0; c < 4; c++)
#pragma unroll
      for (int r = 0; r < 4; r++) o[c][r] *= alpha;
#pragma unroll
    for (int r = 0; r < 4; r++) o4[r] *= alpha;
    asm volatile("s_waitcnt lgkmcnt(0)" ::: "memory");
    short8 pf0 = *(const short8*)&Pl[wave][l * 72 + quad * 8];
    short8 pf1 = *(const short8*)&Pl[wave][l * 72 + 32 + quad * 8];
    short8 vw0 = *(const short8*)&Vt[64 * 72 + quad * 8];
    short8 vw1 = *(const short8*)&Vt[64 * 72 + 32 + quad * 8];
    o4 = __builtin_amdgcn_mfma_f32_16x16x32_bf16(vw0, pf0, o4, 0, 0, 0);
    o4 = __builtin_amdgcn_mfma_f32_16x16x32_bf16(vw1, pf1, o4, 0, 0, 0);
#pragma unroll
    for (int c = 0; c < 4; c++) {
      short8 a0v = *(const short8*)&Vt[(c * 16 + l) * 72 + quad * 8];
      short8 a1v = *(const short8*)&Vt[(c * 16 + l) * 72 + 32 + quad * 8];
      o[c] = __builtin_amdgcn_mfma_f32_16x16x32_bf16(a0v, pf0, o[c], 0, 0, 0);
      o[c] = __builtin_amdgcn_mfma_f32_16x16x32_bf16(a1v, pf1, o[c], 0, 0, 0);
    }
    __syncthreads();
    if (t + 1 < t_end) {
      VSTAGE();
      if (t + 2 < t_end) VLOAD(t + 2);
    }
    __syncthreads();
    cur ^= 1;
  }

  // epilogue: store partials (nontemporal; single-use stream)
  const int gid = hb * 32 + qt * 4 + wave;
  float* po = PO + ((size_t)(seg * NG + gid)) * 1024 + l * 64;
#pragma unroll
  for (int c = 0; c < 4; c++)
    __builtin_nontemporal_store(o[c], (floatx4*)&po[c * 16 + quad * 4]);
  if (quad == 0) {
    __builtin_nontemporal_store(mr, &PM[(size_t)(seg * NG + gid) * 16 + l]);
    __builtin_nontemporal_store(o4[0], &PD[(size_t)(seg * NG + gid) * 16 + l]);
  }
}

// ---------------- combine the 2 KV-split partials -> Cb (bf16) ----------------
__global__ __launch_bounds__(256) void attn_combine(
    const float* __restrict__ PO, const float* __restrict__ PM, const float* __restrict__ PD,
    unsigned short* __restrict__ Cb)
{
  const int tid = threadIdx.x, wave = tid >> 6, lane = tid & 63;
  const int quad = lane >> 4, l = lane & 15;
  const int gid = blockIdx.x * 4 + wave;       // 0..2047
  const int hb = gid >> 5, qt = (gid >> 2) & 7, wv = gid & 3;
  const int b = hb >> 4, h = hb & 15;
  const int q = qt * 64 + wv * 16 + l;

  float m0 = __builtin_nontemporal_load(&PM[(size_t)gid * 16 + l]);
  float m1 = __builtin_nontemporal_load(&PM[(size_t)(NG + gid) * 16 + l]);
  float d0 = __builtin_nontemporal_load(&PD[(size_t)gid * 16 + l]);
  float d1 = __builtin_nontemporal_load(&PD[(size_t)(NG + gid) * 16 + l]);
  float M = fmaxf(m0, m1);
  float a0 = EXP2F(m0 - M), a1 = EXP2F(m1 - M);
  float inv = 1.0f / (d0 * a0 + d1 * a1);
  a0 *= inv; a1 *= inv;

  const fx4* p0 = (const fx4*)(PO + (size_t)gid * 1024 + l * 64 + quad * 16);
  const fx4* p1 = (const fx4*)((const float*)p0 + (size_t)NG * 1024);
  unsigned short* cp = Cb + (size_t)(b * QL + q) * EMB + h * HD + quad * 16;
#pragma unroll
  for (int v = 0; v < 4; v++) {
    fx4 x0 = __builtin_nontemporal_load(p0 + v);
    fx4 x1 = __builtin_nontemporal_load(p1 + v);
    ushort4 w4;
    w4.x = f2b(x0.x * a0 + x1.x * a1);
    w4.y = f2b(x0.y * a0 + x1.y * a1);
    w4.z = f2b(x0.z * a0 + x1.z * a1);
    w4.w = f2b(x0.w * a0 + x1.w * a1);
    *(ushort4*)(cp + v * 4) = w4;
  }
}

extern "C" void kernel_launch(void* const* d_in, const int* in_sizes, int n_in,
                              void* d_out, int out_size, void* d_ws, size_t ws_size,
                              hipStream_t stream) {
  const float* hid  = (const float*)d_in[0];
  const float* mask = (const float*)d_in[1];
  const float* kc   = (const float*)d_in[2];
  const float* vc   = (const float*)d_in[3];
  const float* Wq   = (const float*)d_in[4];
  const float* bq   = (const float*)d_in[5];
  const float* Wk   = (const float*)d_in[6];
  const float* bk   = (const float*)d_in[7];
  const float* Wv   = (const float*)d_in[8];
  const float* bv   = (const float*)d_in[9];
  const float* Wo   = (const float*)d_in[10];
  const float* bo   = (const float*)d_in[11];

  float* out_f = (float*)d_out;
  float* kf = out_f + (size_t)BZv * QL * EMB;
  float* vf = kf + (size_t)BZv * KVL * EMB;

  char* p = (char*)d_ws;
  unsigned short* Xb  = (unsigned short*)p; p += (size_t)BZv * QL * EMB * 2;
  unsigned short* Wqb = (unsigned short*)p; p += (size_t)EMB * EMB * 2;
  unsigned short* Wkb = (unsigned short*)p; p += (size_t)EMB * EMB * 2;
  unsigned short* Wvb = (unsigned short*)p; p += (size_t)EMB * EMB * 2;
  unsigned short* Wob = (unsigned short*)p; p += (size_t)EMB * EMB * 2;
  unsigned short* Qb  = (unsigned short*)p; p += (size_t)BZv * QL * EMB * 2;
  unsigned short* Kb  = (unsigned short*)p; p += (size_t)BZv * KVL * EMB * 2;
  unsigned short* Vb  = (unsigned short*)p; p += (size_t)BZv * KVL * EMB * 2;
  unsigned short* Cb  = (unsigned short*)p; p += (size_t)BZv * QL * EMB * 2;
  unsigned short* wbp = (unsigned short*)p; p += (size_t)BZv * KVL * 2;
  float* POp = (float*)p; p += (size_t)2 * NG * 1024 * 4;
  float* PMp = (float*)p; p += (size_t)2 * NG * 16 * 4;
  float* PDp = (float*)p; p += (size_t)2 * NG * 16 * 4;

  prep_kernel<<<1793, 256, 0, stream>>>(hid, Wq, Wk, Wv, Wo, kc, vc, mask,
                                        Xb, Wqb, Wkb, Wvb, Wob, Kb, Vb, kf, vf, wbp);
  qkv_gemm<<<dim3(48, 16), 256, 0, stream>>>(Xb, Wqb, Wkb, Wvb, bq, bk, bv, mask,
                                             Qb, Kb, Vb, kf, vf);
  attn_kernel<<<1024, 256, 0, stream>>>(Qb, Kb, Vb, wbp, POp, PMp, PDp);
  attn_combine<<<512, 256, 0, stream>>>(POp, PMp, PDp, Cb);
  oproj_gemm<<<dim3(16, 32), 256, 0, stream>>>(Cb, Wob, bo, out_f);
}